// Round 1
// baseline (75199.487 us; speedup 1.0000x reference)
//
#include <hip/hip_runtime.h>
#include <hip/hip_bf16.h>
#include <math.h>

#define Bx    128
#define Pp    196
#define ENCd  512
#define EMBd  256
#define DECd  512
#define ATTd  256
#define Vv    2048
#define MAXLEN 257
#define Tt    256
#define KC    32

__device__ __forceinline__ float wave_sum(float v) {
#pragma unroll
    for (int off = 32; off > 0; off >>= 1) v += __shfl_xor(v, off, 64);
    return v;
}

__device__ __forceinline__ float sigmoidf(float x) { return 1.f / (1.f + __expf(-x)); }

// ---------------- init: mean_enc -> h0, c0 ----------------
__global__ __launch_bounds__(256) void init_state_kernel(
    const float* __restrict__ enc, const float* __restrict__ Wh, const float* __restrict__ bh,
    const float* __restrict__ Wc, const float* __restrict__ bc,
    float* __restrict__ h0, float* __restrict__ c0)
{
    int b = blockIdx.x;
    __shared__ float mean_s[ENCd];
    for (int k = threadIdx.x; k < ENCd; k += 256) {
        const float* base = enc + (size_t)b * Pp * ENCd + k;
        float s = 0.f;
        for (int p = 0; p < Pp; ++p) s += base[(size_t)p * ENCd];
        mean_s[k] = s * (1.0f / (float)Pp);
    }
    __syncthreads();
    int wave = threadIdx.x >> 6, lane = threadIdx.x & 63;
    float m0[8];
#pragma unroll
    for (int i = 0; i < 8; ++i) m0[i] = mean_s[lane * 8 + i];
    for (int j = wave; j < DECd; j += 4) {
        const float* wr = Wh + (size_t)j * ENCd + lane * 8;
        float s = 0.f;
#pragma unroll
        for (int i = 0; i < 8; ++i) s += m0[i] * wr[i];
        s = wave_sum(s);
        if (lane == 0) h0[(size_t)b * DECd + j] = s + bh[j];
        const float* wr2 = Wc + (size_t)j * ENCd + lane * 8;
        float s2 = 0.f;
#pragma unroll
        for (int i = 0; i < 8; ++i) s2 += m0[i] * wr2[i];
        s2 = wave_sum(s2);
        if (lane == 0) c0[(size_t)b * DECd + j] = s2 + bc[j];
    }
}

// ---------------- att1 = enc @ W_enc_att^T + b (one-time GEMM) ----------------
// grid (ATT/64, (B*P)/16), block 256
__global__ __launch_bounds__(256) void att1_kernel(
    const float* __restrict__ A, const float* __restrict__ W,
    const float* __restrict__ bias, float* __restrict__ C)
{
    __shared__ float As[16][KC + 1];
    __shared__ float Ws[64][KC + 1];
    int tn = threadIdx.x & 15, tb = threadIdx.x >> 4;
    int n0 = blockIdx.x * 64;
    int m0 = blockIdx.y * 16;
    float a0 = 0, a1 = 0, a2 = 0, a3 = 0;
    for (int k0 = 0; k0 < ENCd; k0 += KC) {
        for (int e = threadIdx.x; e < 16 * KC; e += 256) {
            int r = e >> 5, cix = e & 31;
            As[r][cix] = A[(size_t)(m0 + r) * ENCd + k0 + cix];
        }
        for (int e = threadIdx.x; e < 64 * KC; e += 256) {
            int r = e >> 5, cix = e & 31;
            Ws[r][cix] = W[(size_t)(n0 + r) * ENCd + k0 + cix];
        }
        __syncthreads();
#pragma unroll
        for (int kk = 0; kk < KC; ++kk) {
            float a = As[tb][kk];
            a0 += a * Ws[tn][kk];
            a1 += a * Ws[16 + tn][kk];
            a2 += a * Ws[32 + tn][kk];
            a3 += a * Ws[48 + tn][kk];
        }
        __syncthreads();
    }
    float* out = C + (size_t)(m0 + tb) * ATTd + n0;
    out[tn]      = a0 + bias[n0 + tn];
    out[16 + tn] = a1 + bias[n0 + 16 + tn];
    out[32 + tn] = a2 + bias[n0 + 32 + tn];
    out[48 + tn] = a3 + bias[n0 + 48 + tn];
}

// ---------------- per-step attention: att2 -> e -> softmax -> ctx ----------------
// grid B, block 256
__global__ __launch_bounds__(256) void attn_step_kernel(
    const float* __restrict__ hin, const float* __restrict__ att1,
    const float* __restrict__ enc, const float* __restrict__ Wdec,
    const float* __restrict__ bdec, const float* __restrict__ wfull_p,
    const float* __restrict__ bfull_p, const int* __restrict__ cap_len,
    float* __restrict__ ctx, float* __restrict__ alphas, int t)
{
    int b = blockIdx.x;
    int tid = threadIdx.x;
    int declen = cap_len[b] - 1;
    float* aout = alphas + ((size_t)b * Tt + t) * Pp;
    if (t >= declen) {
        for (int p = tid; p < Pp; p += 256) aout[p] = 0.f;
        return;
    }
    __shared__ float hs[DECd];
    __shared__ float att2[ATTd];
    __shared__ float wf[ATTd];
    __shared__ float ev[256];
    __shared__ float red[4];
    for (int k = tid; k < DECd; k += 256) hs[k] = hin[(size_t)b * DECd + k];
    if (tid < ATTd) wf[tid] = wfull_p[tid];
    if (tid >= Pp) ev[tid] = -INFINITY;
    __syncthreads();
    int wave = tid >> 6, lane = tid & 63;
    float hreg[8];
#pragma unroll
    for (int i = 0; i < 8; ++i) hreg[i] = hs[lane * 8 + i];
    // att2[j] = h . Wdec[j,:] + bdec[j]  (wave-dot, coalesced 2KB row reads)
    for (int jj = 0; jj < 64; ++jj) {
        int j = (wave << 6) + jj;
        const float* wr = Wdec + (size_t)j * DECd + lane * 8;
        float s = 0.f;
#pragma unroll
        for (int i = 0; i < 8; ++i) s += hreg[i] * wr[i];
        s = wave_sum(s);
        if (lane == 0) att2[j] = s + bdec[j];
    }
    __syncthreads();
    float bfull = bfull_p[0];
    // e[p] = relu(att1[b,p,:] + att2) . wfull + bfull
    for (int p = wave; p < Pp; p += 4) {
        const float* a1 = att1 + ((size_t)b * Pp + p) * ATTd + lane * 4;
        float4 av = *(const float4*)a1;
        float4 t2 = *(const float4*)(att2 + lane * 4);
        float4 wv = *(const float4*)(wf + lane * 4);
        float s;
        s  = fmaxf(av.x + t2.x, 0.f) * wv.x;
        s += fmaxf(av.y + t2.y, 0.f) * wv.y;
        s += fmaxf(av.z + t2.z, 0.f) * wv.z;
        s += fmaxf(av.w + t2.w, 0.f) * wv.w;
        s = wave_sum(s);
        if (lane == 0) ev[p] = s + bfull;
    }
    __syncthreads();
    // softmax over 196 (padded to 256 with -inf)
    float v = ev[tid];
    {
        float m = v;
#pragma unroll
        for (int off = 32; off > 0; off >>= 1) m = fmaxf(m, __shfl_xor(m, off, 64));
        if (lane == 0) red[wave] = m;
    }
    __syncthreads();
    float mx = fmaxf(fmaxf(red[0], red[1]), fmaxf(red[2], red[3]));
    float ex = __expf(v - mx);
    __syncthreads();
    {
        float s = ex;
#pragma unroll
        for (int off = 32; off > 0; off >>= 1) s += __shfl_xor(s, off, 64);
        if (lane == 0) red[wave] = s;
    }
    __syncthreads();
    float inv = 1.f / (red[0] + red[1] + red[2] + red[3]);
    float alpha = ex * inv;
    ev[tid] = alpha;
    if (tid < Pp) aout[tid] = alpha;
    __syncthreads();
    // ctx[k] = sum_p alpha[p] * enc[b,p,k]   (coalesced over k)
    for (int k = tid; k < ENCd; k += 256) {
        const float* eb = enc + (size_t)b * Pp * ENCd + k;
        float s = 0.f;
#pragma unroll 4
        for (int p = 0; p < Pp; ++p) s += ev[p] * eb[(size_t)p * ENCd];
        ctx[(size_t)b * ENCd + k] = s;
    }
}

// ---------------- gates GEMM + LSTM cell ----------------
// C[b, j, gate] = [emb_t | ctx | h][b,:] . [W_ih | W_hh][gate*512+j,:]
// grid (512/16, 128/16) = (32, 8), block 256
__global__ __launch_bounds__(256) void gates_step_kernel(
    const float* __restrict__ hin, const float* __restrict__ cin,
    const float* __restrict__ ctx, const float* __restrict__ emb,
    const int* __restrict__ caps, const float* __restrict__ Wih,
    const float* __restrict__ bih, const float* __restrict__ Whh,
    const float* __restrict__ bhh, const int* __restrict__ cap_len,
    float* __restrict__ hout, float* __restrict__ cout_, int t)
{
    __shared__ float As[16][KC + 1];
    __shared__ float Ws[64][KC + 1];
    __shared__ int capidx[16];
    int tj = threadIdx.x & 15, tb = threadIdx.x >> 4;
    int j0 = blockIdx.x * 16;
    int b0 = blockIdx.y * 16;
    if (threadIdx.x < 16) capidx[threadIdx.x] = caps[(b0 + threadIdx.x) * MAXLEN + t];
    __syncthreads();
    float acc_i = 0, acc_f = 0, acc_g = 0, acc_o = 0;
    for (int k0 = 0; k0 < 1280; k0 += KC) {
        for (int e = threadIdx.x; e < 16 * KC; e += 256) {
            int r = e >> 5, cix = e & 31;
            int k = k0 + cix;
            int b = b0 + r;
            float vA;
            if (k < EMBd)          vA = emb[(size_t)capidx[r] * EMBd + k];
            else if (k < EMBd + ENCd) vA = ctx[(size_t)b * ENCd + (k - EMBd)];
            else                   vA = hin[(size_t)b * DECd + (k - EMBd - ENCd)];
            As[r][cix] = vA;
        }
        for (int e = threadIdx.x; e < 64 * KC; e += 256) {
            int r = e >> 5, cix = e & 31;
            int g = r >> 4, jj = r & 15;
            int wrow = g * 512 + j0 + jj;
            int k = k0 + cix;
            float vW = (k < 768) ? Wih[(size_t)wrow * 768 + k]
                                 : Whh[(size_t)wrow * 512 + (k - 768)];
            Ws[r][cix] = vW;
        }
        __syncthreads();
#pragma unroll
        for (int kk = 0; kk < KC; ++kk) {
            float a = As[tb][kk];
            acc_i += a * Ws[tj][kk];
            acc_f += a * Ws[16 + tj][kk];
            acc_g += a * Ws[32 + tj][kk];
            acc_o += a * Ws[48 + tj][kk];
        }
        __syncthreads();
    }
    int b = b0 + tb, j = j0 + tj;
    float gi = acc_i + bih[j]        + bhh[j];
    float gf = acc_f + bih[512 + j]  + bhh[512 + j];
    float gg = acc_g + bih[1024 + j] + bhh[1024 + j];
    float go = acc_o + bih[1536 + j] + bhh[1536 + j];
    float cold = cin[(size_t)b * DECd + j];
    float hold = hin[(size_t)b * DECd + j];
    float cn = sigmoidf(gf) * cold + sigmoidf(gi) * tanhf(gg);
    float hn = sigmoidf(go) * tanhf(cn);
    bool active = t < (cap_len[b] - 1);
    hout[(size_t)b * DECd + j] = active ? hn : hold;
    cout_[(size_t)b * DECd + j] = active ? cn : cold;
}

// ---------------- preds GEMM: h_next @ W_fc^T + b_fc, masked write ----------------
// grid (2048/64, 128/16) = (32, 8), block 256
__global__ __launch_bounds__(256) void preds_step_kernel(
    const float* __restrict__ h, const float* __restrict__ Wfc,
    const float* __restrict__ bfc, const int* __restrict__ cap_len,
    float* __restrict__ preds, int t)
{
    __shared__ float As[16][KC + 1];
    __shared__ float Ws[64][KC + 1];
    int tn = threadIdx.x & 15, tb = threadIdx.x >> 4;
    int n0 = blockIdx.x * 64;
    int b0 = blockIdx.y * 16;
    float a0 = 0, a1 = 0, a2 = 0, a3 = 0;
    for (int k0 = 0; k0 < DECd; k0 += KC) {
        for (int e = threadIdx.x; e < 16 * KC; e += 256) {
            int r = e >> 5, cix = e & 31;
            As[r][cix] = h[(size_t)(b0 + r) * DECd + k0 + cix];
        }
        for (int e = threadIdx.x; e < 64 * KC; e += 256) {
            int r = e >> 5, cix = e & 31;
            Ws[r][cix] = Wfc[(size_t)(n0 + r) * DECd + k0 + cix];
        }
        __syncthreads();
#pragma unroll
        for (int kk = 0; kk < KC; ++kk) {
            float a = As[tb][kk];
            a0 += a * Ws[tn][kk];
            a1 += a * Ws[16 + tn][kk];
            a2 += a * Ws[32 + tn][kk];
            a3 += a * Ws[48 + tn][kk];
        }
        __syncthreads();
    }
    int b = b0 + tb;
    bool active = t < (cap_len[b] - 1);
    float* out = preds + ((size_t)b * Tt + t) * Vv + n0;
    out[tn]      = active ? (a0 + bfc[n0 + tn])      : 0.f;
    out[16 + tn] = active ? (a1 + bfc[n0 + 16 + tn]) : 0.f;
    out[32 + tn] = active ? (a2 + bfc[n0 + 32 + tn]) : 0.f;
    out[48 + tn] = active ? (a3 + bfc[n0 + 48 + tn]) : 0.f;
}

extern "C" void kernel_launch(void* const* d_in, const int* in_sizes, int n_in,
                              void* d_out, int out_size, void* d_ws, size_t ws_size,
                              hipStream_t stream) {
    const float* enc      = (const float*)d_in[0];
    const int*   caps     = (const int*)d_in[1];
    const int*   cap_len  = (const int*)d_in[2];
    const float* embedding= (const float*)d_in[3];
    const float* Wenc     = (const float*)d_in[4];
    const float* benc     = (const float*)d_in[5];
    const float* Wdec     = (const float*)d_in[6];
    const float* bdec     = (const float*)d_in[7];
    const float* wfull    = (const float*)d_in[8];
    const float* bfull    = (const float*)d_in[9];
    const float* Wih      = (const float*)d_in[10];
    const float* bih      = (const float*)d_in[11];
    const float* Whh      = (const float*)d_in[12];
    const float* bhh      = (const float*)d_in[13];
    const float* Winh     = (const float*)d_in[14];
    const float* binh     = (const float*)d_in[15];
    const float* Winc     = (const float*)d_in[16];
    const float* binc     = (const float*)d_in[17];
    const float* Wfc      = (const float*)d_in[18];
    const float* bfc      = (const float*)d_in[19];

    float* preds  = (float*)d_out;                         // B*T*V
    float* alphas = preds + (size_t)Bx * Tt * Vv;          // B*T*P

    float* ws   = (float*)d_ws;
    float* att1 = ws;                                      // B*P*ATT = 6,422,528
    float* hb0  = att1 + (size_t)Bx * Pp * ATTd;
    float* hb1  = hb0 + (size_t)Bx * DECd;
    float* cb0  = hb1 + (size_t)Bx * DECd;
    float* cb1  = cb0 + (size_t)Bx * DECd;
    float* ctx  = cb1 + (size_t)Bx * DECd;
    float* hbuf[2] = {hb0, hb1};
    float* cbuf[2] = {cb0, cb1};

    init_state_kernel<<<Bx, 256, 0, stream>>>(enc, Winh, binh, Winc, binc, hb0, cb0);
    att1_kernel<<<dim3(ATTd / 64, (Bx * Pp) / 16), 256, 0, stream>>>(enc, Wenc, benc, att1);

    for (int t = 0; t < Tt; ++t) {
        const float* hin = hbuf[t & 1];
        const float* cin = cbuf[t & 1];
        float* hout = hbuf[(t + 1) & 1];
        float* cout_ = cbuf[(t + 1) & 1];
        attn_step_kernel<<<Bx, 256, 0, stream>>>(hin, att1, enc, Wdec, bdec, wfull,
                                                 bfull, cap_len, ctx, alphas, t);
        gates_step_kernel<<<dim3(32, 8), 256, 0, stream>>>(hin, cin, ctx, embedding, caps,
                                                           Wih, bih, Whh, bhh, cap_len,
                                                           hout, cout_, t);
        preds_step_kernel<<<dim3(32, 8), 256, 0, stream>>>(hout, Wfc, bfc, cap_len, preds, t);
    }
}

// Round 2
// 42968.637 us; speedup vs baseline: 1.7501x; 1.7501x over previous
//
#include <hip/hip_runtime.h>
#include <hip/hip_bf16.h>
#include <math.h>

#define Bx    128
#define Pp    196
#define ENCd  512
#define EMBd  256
#define DECd  512
#define ATTd  256
#define Vv    2048
#define MAXLEN 257
#define Tt    256
#define KC    32

__device__ __forceinline__ float wave_sum(float v) {
#pragma unroll
    for (int off = 32; off > 0; off >>= 1) v += __shfl_xor(v, off, 64);
    return v;
}

__device__ __forceinline__ float sigmoidf(float x) { return 1.f / (1.f + __expf(-x)); }

// ---------------- transpose Wdec (ATT x DEC) -> WdecT (DEC x ATT), once ----------------
__global__ __launch_bounds__(256) void transpose_wdec_kernel(
    const float* __restrict__ Wdec, float* __restrict__ WdT)
{
    int k = blockIdx.x;            // 0..511
    int j = threadIdx.x;           // 0..255
    WdT[(size_t)k * ATTd + j] = Wdec[(size_t)j * DECd + k];
}

// ---------------- init: mean_enc -> h0, c0 ----------------
__global__ __launch_bounds__(256) void init_state_kernel(
    const float* __restrict__ enc, const float* __restrict__ Wh, const float* __restrict__ bh,
    const float* __restrict__ Wc, const float* __restrict__ bc,
    float* __restrict__ h0, float* __restrict__ c0)
{
    int b = blockIdx.x;
    __shared__ float mean_s[ENCd];
    for (int k = threadIdx.x; k < ENCd; k += 256) {
        const float* base = enc + (size_t)b * Pp * ENCd + k;
        float s = 0.f;
        for (int p = 0; p < Pp; ++p) s += base[(size_t)p * ENCd];
        mean_s[k] = s * (1.0f / (float)Pp);
    }
    __syncthreads();
    int wave = threadIdx.x >> 6, lane = threadIdx.x & 63;
    float m0[8];
#pragma unroll
    for (int i = 0; i < 8; ++i) m0[i] = mean_s[lane * 8 + i];
    for (int j = wave; j < DECd; j += 4) {
        const float* wr = Wh + (size_t)j * ENCd + lane * 8;
        float s = 0.f;
#pragma unroll
        for (int i = 0; i < 8; ++i) s += m0[i] * wr[i];
        s = wave_sum(s);
        if (lane == 0) h0[(size_t)b * DECd + j] = s + bh[j];
        const float* wr2 = Wc + (size_t)j * ENCd + lane * 8;
        float s2 = 0.f;
#pragma unroll
        for (int i = 0; i < 8; ++i) s2 += m0[i] * wr2[i];
        s2 = wave_sum(s2);
        if (lane == 0) c0[(size_t)b * DECd + j] = s2 + bc[j];
    }
}

// ---------------- att1 = enc @ W_enc_att^T + b (one-time GEMM) ----------------
// A: (25088 x 512), W: (256 x 512), out: (25088 x 256)
// grid (256/64=4, 25088/32=784), block 256; thread tile 2m x 4n
__global__ __launch_bounds__(256) void att1_tiled_kernel(
    const float* __restrict__ A, const float* __restrict__ W,
    const float* __restrict__ bias, float* __restrict__ C)
{
    __shared__ float As[KC][36];
    __shared__ float Ws[KC][68];
    int tid = threadIdx.x;
    int tn = tid & 15, tb = tid >> 4;
    int n0 = blockIdx.x * 64;
    int m0 = blockIdx.y * 32;
    float c00=0,c01=0,c02=0,c03=0,c10=0,c11=0,c12=0,c13=0;
    int kc = tid & 31;
    for (int k0 = 0; k0 < ENCd; k0 += KC) {
        {
            int mm = tid >> 5;
#pragma unroll
            for (int i = 0; i < 4; ++i, mm += 8)
                As[kc][mm] = A[(size_t)(m0 + mm) * ENCd + k0 + kc];
            int nn = tid >> 5;
#pragma unroll
            for (int i = 0; i < 8; ++i, nn += 8)
                Ws[kc][nn] = W[(size_t)(n0 + nn) * ENCd + k0 + kc];
        }
        __syncthreads();
#pragma unroll
        for (int kk = 0; kk < KC; ++kk) {
            float2 a = *(const float2*)&As[kk][2 * tb];
            float4 w = *(const float4*)&Ws[kk][4 * tn];
            c00 += a.x*w.x; c01 += a.x*w.y; c02 += a.x*w.z; c03 += a.x*w.w;
            c10 += a.y*w.x; c11 += a.y*w.y; c12 += a.y*w.z; c13 += a.y*w.w;
        }
        __syncthreads();
    }
    int n = n0 + 4 * tn;
    float4 bv = *(const float4*)&bias[n];
    int m = m0 + 2 * tb;
    float4 o0 = make_float4(c00+bv.x, c01+bv.y, c02+bv.z, c03+bv.w);
    float4 o1 = make_float4(c10+bv.x, c11+bv.y, c12+bv.z, c13+bv.w);
    *(float4*)&C[(size_t)m * ATTd + n] = o0;
    *(float4*)&C[(size_t)(m + 1) * ATTd + n] = o1;
}

// ---------------- per-step attention (fused att2+e+softmax+ctx) ----------------
// grid (B, 2), block 256. kh = blockIdx.y selects ctx k-half.
__global__ __launch_bounds__(256) void attn_step_kernel(
    const float* __restrict__ hin, const float* __restrict__ att1,
    const float* __restrict__ enc, const float* __restrict__ WdT,
    const float* __restrict__ bdec, const float* __restrict__ wfull_p,
    const float* __restrict__ bfull_p, const int* __restrict__ cap_len,
    float* __restrict__ ctx, float* __restrict__ alphas, int t)
{
    int b = blockIdx.x, kh = blockIdx.y, tid = threadIdx.x;
    int declen = cap_len[b] - 1;
    float* aout = alphas + ((size_t)b * Tt + t) * Pp;
    if (t >= declen) {
        if (kh == 0) for (int p = tid; p < Pp; p += 256) aout[p] = 0.f;
        return;
    }
    __shared__ float hs[DECd];
    __shared__ float a2s[ATTd];
    __shared__ float wfs[ATTd];
    __shared__ float ev[256];
    __shared__ float red[4];
    for (int k = tid; k < DECd; k += 256) hs[k] = hin[(size_t)b * DECd + k];
    wfs[tid] = wfull_p[tid];
    __syncthreads();
    // att2[j] = h . WdecT[:,j] + bdec[j]   (thread-per-output, coalesced)
    {
        const float* Wp = WdT + tid;
        float a0 = 0, a1 = 0, a2 = 0, a3 = 0;
        for (int k = 0; k < DECd; k += 4) {
            a0 += hs[k]     * Wp[(size_t)k * ATTd];
            a1 += hs[k + 1] * Wp[(size_t)(k + 1) * ATTd];
            a2 += hs[k + 2] * Wp[(size_t)(k + 2) * ATTd];
            a3 += hs[k + 3] * Wp[(size_t)(k + 3) * ATTd];
        }
        a2s[tid] = (a0 + a1) + (a2 + a3) + bdec[tid];
    }
    __syncthreads();
    int wave = tid >> 6, lane = tid & 63;
    float bfull = bfull_p[0];
    // e[p] = relu(att1[b,p,:] + att2) . wfull + bfull
    for (int p = wave; p < Pp; p += 4) {
        float4 av = *(const float4*)(att1 + ((size_t)b * Pp + p) * ATTd + lane * 4);
        float4 t2 = *(const float4*)&a2s[lane * 4];
        float4 wv = *(const float4*)&wfs[lane * 4];
        float s;
        s  = fmaxf(av.x + t2.x, 0.f) * wv.x;
        s += fmaxf(av.y + t2.y, 0.f) * wv.y;
        s += fmaxf(av.z + t2.z, 0.f) * wv.z;
        s += fmaxf(av.w + t2.w, 0.f) * wv.w;
        s = wave_sum(s);
        if (lane == 0) ev[p] = s + bfull;
    }
    __syncthreads();
    // softmax over 196 (pad to 256 with -inf)
    float v = (tid < Pp) ? ev[tid] : -INFINITY;
    {
        float m = v;
#pragma unroll
        for (int off = 32; off > 0; off >>= 1) m = fmaxf(m, __shfl_xor(m, off, 64));
        if (lane == 0) red[wave] = m;
    }
    __syncthreads();
    float mx = fmaxf(fmaxf(red[0], red[1]), fmaxf(red[2], red[3]));
    float ex = __expf(v - mx);
    __syncthreads();
    {
        float s = ex;
#pragma unroll
        for (int off = 32; off > 0; off >>= 1) s += __shfl_xor(s, off, 64);
        if (lane == 0) red[wave] = s;
    }
    __syncthreads();
    float inv = 1.f / (red[0] + red[1] + red[2] + red[3]);
    float alpha = ex * inv;
    ev[tid] = alpha;                      // reuse as alpha store
    if (kh == 0 && tid < Pp) aout[tid] = alpha;
    __syncthreads();
    // ctx[k] for this block's k-half
    int k = kh * 256 + tid;
    const float* eb = enc + (size_t)b * Pp * ENCd + k;
    float s0 = 0, s1 = 0, s2 = 0, s3 = 0;
    for (int p = 0; p < Pp; p += 4) {
        s0 += ev[p]     * eb[(size_t)p * ENCd];
        s1 += ev[p + 1] * eb[(size_t)(p + 1) * ENCd];
        s2 += ev[p + 2] * eb[(size_t)(p + 2) * ENCd];
        s3 += ev[p + 3] * eb[(size_t)(p + 3) * ENCd];
    }
    ctx[(size_t)b * ENCd + k] = (s0 + s1) + (s2 + s3);
}

// ---------------- gates GEMM + LSTM cell ----------------
// x = [emb | ctx | h] (128 x 1280); W rows: gate g, col j -> row g*512+j
// grid (512/16=32 j-tiles, 128/32=4 b-tiles), block 256; thread: 2 b x 4 gates of one j
__global__ __launch_bounds__(256) void gates_step_kernel(
    const float* __restrict__ hin, const float* __restrict__ cin,
    const float* __restrict__ ctx, const float* __restrict__ emb,
    const int* __restrict__ caps, const float* __restrict__ Wih,
    const float* __restrict__ bih, const float* __restrict__ Whh,
    const float* __restrict__ bhh, const int* __restrict__ cap_len,
    float* __restrict__ hout, float* __restrict__ cout_, int t)
{
    int tid = threadIdx.x;
    int j0 = blockIdx.x * 16;
    int b0 = blockIdx.y * 32;
    if (t >= cap_len[b0] - 1) return;   // lengths sorted desc: whole block inactive
    __shared__ float As[KC][36];
    __shared__ float Ws[KC][68];
    __shared__ int capidx[32];
    if (tid < 32) capidx[tid] = caps[(b0 + tid) * MAXLEN + t];
    __syncthreads();
    int tj = tid & 15, tb = tid >> 4;
    int kc = tid & 31;
    float c00=0,c01=0,c02=0,c03=0,c10=0,c11=0,c12=0,c13=0;
    for (int k0 = 0; k0 < EMBd + ENCd + DECd; k0 += KC) {
        {
            int bb = tid >> 5;
            int k = k0 + kc;
#pragma unroll
            for (int i = 0; i < 4; ++i, bb += 8) {
                float vA;
                if (k0 < EMBd)             vA = emb[(size_t)capidx[bb] * EMBd + k];
                else if (k0 < EMBd + ENCd) vA = ctx[(size_t)(b0 + bb) * ENCd + (k - EMBd)];
                else                       vA = hin[(size_t)(b0 + bb) * DECd + (k - EMBd - ENCd)];
                As[kc][bb] = vA;
            }
            int col = tid >> 5;
#pragma unroll
            for (int i = 0; i < 8; ++i, col += 8) {
                int jj = col & 15, g = col >> 4;
                int row = g * DECd + j0 + jj;
                float vW = (k0 < EMBd + ENCd) ? Wih[(size_t)row * (EMBd + ENCd) + k]
                                              : Whh[(size_t)row * DECd + (k - EMBd - ENCd)];
                Ws[kc][4 * jj + g] = vW;
            }
        }
        __syncthreads();
#pragma unroll
        for (int kk = 0; kk < KC; ++kk) {
            float2 a = *(const float2*)&As[kk][2 * tb];
            float4 w = *(const float4*)&Ws[kk][4 * tj];
            c00 += a.x*w.x; c01 += a.x*w.y; c02 += a.x*w.z; c03 += a.x*w.w;
            c10 += a.y*w.x; c11 += a.y*w.y; c12 += a.y*w.z; c13 += a.y*w.w;
        }
        __syncthreads();
    }
    int j = j0 + tj;
    float bi = bih[j] + bhh[j];
    float bf = bih[DECd + j] + bhh[DECd + j];
    float bg = bih[2 * DECd + j] + bhh[2 * DECd + j];
    float bo = bih[3 * DECd + j] + bhh[3 * DECd + j];
#pragma unroll
    for (int bb2 = 0; bb2 < 2; ++bb2) {
        int b = b0 + 2 * tb + bb2;
        if (t < cap_len[b] - 1) {
            float gi = (bb2 ? c10 : c00) + bi;
            float gf = (bb2 ? c11 : c01) + bf;
            float gg = (bb2 ? c12 : c02) + bg;
            float go = (bb2 ? c13 : c03) + bo;
            float cold = cin[(size_t)b * DECd + j];
            float cn = sigmoidf(gf) * cold + sigmoidf(gi) * tanhf(gg);
            float hn = sigmoidf(go) * tanhf(cn);
            hout[(size_t)b * DECd + j] = hn;
            cout_[(size_t)b * DECd + j] = cn;
        }
    }
}

// ---------------- preds GEMM: h_next @ W_fc^T + b_fc, masked write ----------------
// grid (2048/64=32, 128/32=4), block 256; thread tile 2b x 4n
__global__ __launch_bounds__(256) void preds_step_kernel(
    const float* __restrict__ h, const float* __restrict__ Wfc,
    const float* __restrict__ bfc, const int* __restrict__ cap_len,
    float* __restrict__ preds, int t)
{
    int tid = threadIdx.x;
    int tn = tid & 15, tb = tid >> 4;
    int n0 = blockIdx.x * 64;
    int b0 = blockIdx.y * 32;
    int n = n0 + 4 * tn;
    if (t >= cap_len[b0] - 1) {          // whole block inactive -> zeros
        float4 z = make_float4(0.f, 0.f, 0.f, 0.f);
        int b = b0 + 2 * tb;
        *(float4*)&preds[((size_t)b * Tt + t) * Vv + n] = z;
        *(float4*)&preds[((size_t)(b + 1) * Tt + t) * Vv + n] = z;
        return;
    }
    __shared__ float As[KC][36];
    __shared__ float Ws[KC][68];
    int kc = tid & 31;
    float c00=0,c01=0,c02=0,c03=0,c10=0,c11=0,c12=0,c13=0;
    for (int k0 = 0; k0 < DECd; k0 += KC) {
        {
            int bb = tid >> 5;
#pragma unroll
            for (int i = 0; i < 4; ++i, bb += 8)
                As[kc][bb] = h[(size_t)(b0 + bb) * DECd + k0 + kc];
            int nn = tid >> 5;
#pragma unroll
            for (int i = 0; i < 8; ++i, nn += 8)
                Ws[kc][nn] = Wfc[(size_t)(n0 + nn) * DECd + k0 + kc];
        }
        __syncthreads();
#pragma unroll
        for (int kk = 0; kk < KC; ++kk) {
            float2 a = *(const float2*)&As[kk][2 * tb];
            float4 w = *(const float4*)&Ws[kk][4 * tn];
            c00 += a.x*w.x; c01 += a.x*w.y; c02 += a.x*w.z; c03 += a.x*w.w;
            c10 += a.y*w.x; c11 += a.y*w.y; c12 += a.y*w.z; c13 += a.y*w.w;
        }
        __syncthreads();
    }
    float4 bv = *(const float4*)&bfc[n];
#pragma unroll
    for (int bb2 = 0; bb2 < 2; ++bb2) {
        int b = b0 + 2 * tb + bb2;
        bool act = t < (cap_len[b] - 1);
        float4 o;
        o.x = act ? (bb2 ? c10 : c00) + bv.x : 0.f;
        o.y = act ? (bb2 ? c11 : c01) + bv.y : 0.f;
        o.z = act ? (bb2 ? c12 : c02) + bv.z : 0.f;
        o.w = act ? (bb2 ? c13 : c03) + bv.w : 0.f;
        *(float4*)&preds[((size_t)b * Tt + t) * Vv + n] = o;
    }
}

extern "C" void kernel_launch(void* const* d_in, const int* in_sizes, int n_in,
                              void* d_out, int out_size, void* d_ws, size_t ws_size,
                              hipStream_t stream) {
    const float* enc      = (const float*)d_in[0];
    const int*   caps     = (const int*)d_in[1];
    const int*   cap_len  = (const int*)d_in[2];
    const float* embedding= (const float*)d_in[3];
    const float* Wenc     = (const float*)d_in[4];
    const float* benc     = (const float*)d_in[5];
    const float* Wdec     = (const float*)d_in[6];
    const float* bdec     = (const float*)d_in[7];
    const float* wfull    = (const float*)d_in[8];
    const float* bfull    = (const float*)d_in[9];
    const float* Wih      = (const float*)d_in[10];
    const float* bih      = (const float*)d_in[11];
    const float* Whh      = (const float*)d_in[12];
    const float* bhh      = (const float*)d_in[13];
    const float* Winh     = (const float*)d_in[14];
    const float* binh     = (const float*)d_in[15];
    const float* Winc     = (const float*)d_in[16];
    const float* binc     = (const float*)d_in[17];
    const float* Wfc      = (const float*)d_in[18];
    const float* bfc      = (const float*)d_in[19];

    float* preds  = (float*)d_out;                         // B*T*V
    float* alphas = preds + (size_t)Bx * Tt * Vv;          // B*T*P

    float* ws   = (float*)d_ws;
    float* att1 = ws;                                      // 25088*256
    float* WdT  = att1 + (size_t)Bx * Pp * ATTd;           // 512*256
    float* hb0  = WdT + (size_t)DECd * ATTd;
    float* hb1  = hb0 + (size_t)Bx * DECd;
    float* cb0  = hb1 + (size_t)Bx * DECd;
    float* cb1  = cb0 + (size_t)Bx * DECd;
    float* ctx  = cb1 + (size_t)Bx * DECd;
    float* hbuf[2] = {hb0, hb1};
    float* cbuf[2] = {cb0, cb1};

    transpose_wdec_kernel<<<DECd, 256, 0, stream>>>(Wdec, WdT);
    init_state_kernel<<<Bx, 256, 0, stream>>>(enc, Winh, binh, Winc, binc, hb0, cb0);
    att1_tiled_kernel<<<dim3(ATTd / 64, (Bx * Pp) / 32), 256, 0, stream>>>(enc, Wenc, benc, att1);

    for (int t = 0; t < Tt; ++t) {
        const float* hin = hbuf[t & 1];
        const float* cin = cbuf[t & 1];
        float* hout = hbuf[(t + 1) & 1];
        float* cout_ = cbuf[(t + 1) & 1];
        attn_step_kernel<<<dim3(Bx, 2), 256, 0, stream>>>(hin, att1, enc, WdT, bdec, wfull,
                                                          bfull, cap_len, ctx, alphas, t);
        gates_step_kernel<<<dim3(32, 4), 256, 0, stream>>>(hin, cin, ctx, embedding, caps,
                                                           Wih, bih, Whh, bhh, cap_len,
                                                           hout, cout_, t);
        preds_step_kernel<<<dim3(32, 4), 256, 0, stream>>>(hout, Wfc, bfc, cap_len, preds, t);
    }
}

// Round 3
// 19057.872 us; speedup vs baseline: 3.9458x; 2.2546x over previous
//
#include <hip/hip_runtime.h>
#include <hip/hip_bf16.h>
#include <math.h>

#define Bx    128
#define Pp    196
#define ENCd  512
#define EMBd  256
#define DECd  512
#define ATTd  256
#define Vv    2048
#define MAXLEN 257
#define Tt    256

__device__ __forceinline__ float wave_sum(float v) {
#pragma unroll
    for (int off = 32; off > 0; off >>= 1) v += __shfl_xor(v, off, 64);
    return v;
}
__device__ __forceinline__ float fsigmoid(float x) { return __frcp_rn(1.f + __expf(-x)); }
__device__ __forceinline__ float ftanh(float x) {
    float e = __expf(2.f * x);
    return fmaf(-2.f, __frcp_rn(e + 1.f), 1.f);   // 1 - 2/(e^{2x}+1); inf-safe
}

// ---------------- init: mean_enc -> h0, c0 ----------------
__global__ __launch_bounds__(256) void init_state_kernel(
    const float* __restrict__ enc, const float* __restrict__ Wh, const float* __restrict__ bh,
    const float* __restrict__ Wc, const float* __restrict__ bc,
    float* __restrict__ h0, float* __restrict__ c0)
{
    int b = blockIdx.x;
    __shared__ float mean_s[ENCd];
    for (int k = threadIdx.x; k < ENCd; k += 256) {
        const float* base = enc + (size_t)b * Pp * ENCd + k;
        float s = 0.f;
        for (int p = 0; p < Pp; ++p) s += base[(size_t)p * ENCd];
        mean_s[k] = s * (1.0f / (float)Pp);
    }
    __syncthreads();
    int wave = threadIdx.x >> 6, lane = threadIdx.x & 63;
    float m0[8];
#pragma unroll
    for (int i = 0; i < 8; ++i) m0[i] = mean_s[lane * 8 + i];
    for (int j = wave; j < DECd; j += 4) {
        const float* wr = Wh + (size_t)j * ENCd + lane * 8;
        float s = 0.f;
#pragma unroll
        for (int i = 0; i < 8; ++i) s += m0[i] * wr[i];
        s = wave_sum(s);
        if (lane == 0) h0[(size_t)b * DECd + j] = s + bh[j];
        const float* wr2 = Wc + (size_t)j * ENCd + lane * 8;
        float s2 = 0.f;
#pragma unroll
        for (int i = 0; i < 8; ++i) s2 += m0[i] * wr2[i];
        s2 = wave_sum(s2);
        if (lane == 0) c0[(size_t)b * DECd + j] = s2 + bc[j];
    }
}

// ---------------- unified tiled GEMM, 32M x 128N block, 4x4 thread tile ----------------
// MODE 0: att1 = enc(25088x512) @ Wenc^T(512x256) + benc   grid (2, 784)
// MODE 1: gates partials: A=[emb|ctx|h](128x1280) @ [Wih|Whh]^T  K-split 4
//         grid (16 nt + 16*ks, 4 bt); N-cols interleaved c=4*jj+g
// MODE 2: preds partials: h(128x512) @ Wfc^T(512x2048)  K-split 4; grid (nt+16*ks, bt)
template<int MODE>
__global__ __launch_bounds__(256) void gemm_kernel(
    const float* __restrict__ Abase, const float* __restrict__ Wa,
    const float* __restrict__ Wb, const float* __restrict__ bias,
    const float* __restrict__ ctxp, const float* __restrict__ embp,
    const int* __restrict__ caps, const int* __restrict__ cap_len,
    float* __restrict__ Cout, int t)
{
    int tid = threadIdx.x;
    int nt, ks, m0;
    if constexpr (MODE == 0) { nt = blockIdx.x; ks = 0; m0 = blockIdx.y * 32; }
    else { nt = blockIdx.x & 15; ks = blockIdx.x >> 4; m0 = blockIdx.y * 32; }
    if constexpr (MODE != 0) { if (t >= cap_len[m0] - 1) return; }  // sorted desc
    constexpr int KT = (MODE == 0) ? 16 : (MODE == 1 ? 10 : 4);
    const int kbase = (MODE == 1) ? ks * 320 : ((MODE == 2) ? ks * 128 : 0);

    __shared__ __align__(16) float As[2][32][36];
    __shared__ __align__(16) float Ws[2][32][132];
    __shared__ int capidx[32];
    if constexpr (MODE == 1) {
        if (tid < 32) capidx[tid] = caps[(m0 + tid) * MAXLEN + t];
        __syncthreads();
    }

    const int arow = tid >> 3, akq = tid & 7;       // A staging: row, k-quad
    const int wc = tid >> 1, wk0 = (tid & 1) * 16;  // W staging: col, k-half
    int wrow;
    if constexpr (MODE == 1) wrow = (wc & 3) * DECd + nt * 32 + (wc >> 2);
    else                     wrow = nt * 128 + wc;

    float4 ar; float4 wr[4];

    auto stage_load = [&](int it) {
        int k0 = kbase + it * 32;
        {
            int k = k0 + 4 * akq;
            const float* src;
            if constexpr (MODE == 1) {
                int b = m0 + arow;
                if (k < EMBd)             src = &embp[(size_t)capidx[arow] * EMBd + k];
                else if (k < EMBd + ENCd) src = &ctxp[(size_t)b * ENCd + (k - EMBd)];
                else                      src = &Abase[(size_t)b * DECd + (k - EMBd - ENCd)];
            } else {
                src = &Abase[(size_t)(m0 + arow) * 512 + k];
            }
            ar = *(const float4*)src;
        }
#pragma unroll
        for (int i = 0; i < 4; ++i) {
            int k = k0 + wk0 + 4 * i;
            const float* wsrc;
            if constexpr (MODE == 1) {
                if (k < EMBd + ENCd) wsrc = &Wa[(size_t)wrow * (EMBd + ENCd) + k];
                else                 wsrc = &Wb[(size_t)wrow * DECd + (k - EMBd - ENCd)];
            } else {
                wsrc = &Wa[(size_t)wrow * 512 + k];
            }
            wr[i] = *(const float4*)wsrc;
        }
    };
    auto stage_store = [&](int s) {
        As[s][4 * akq + 0][arow] = ar.x;
        As[s][4 * akq + 1][arow] = ar.y;
        As[s][4 * akq + 2][arow] = ar.z;
        As[s][4 * akq + 3][arow] = ar.w;
#pragma unroll
        for (int i = 0; i < 4; ++i) {
            Ws[s][wk0 + 4 * i + 0][wc] = wr[i].x;
            Ws[s][wk0 + 4 * i + 1][wc] = wr[i].y;
            Ws[s][wk0 + 4 * i + 2][wc] = wr[i].z;
            Ws[s][wk0 + 4 * i + 3][wc] = wr[i].w;
        }
    };

    const int bq = tid >> 5, nq = tid & 31;
    float4 acc0 = {0,0,0,0}, acc1 = {0,0,0,0}, acc2 = {0,0,0,0}, acc3 = {0,0,0,0};

    stage_load(0); stage_store(0); __syncthreads();
    int s = 0;
    for (int it = 0; it < KT; ++it) {
        if (it + 1 < KT) stage_load(it + 1);
#pragma unroll
        for (int kk = 0; kk < 32; ++kk) {
            float4 a = *(const float4*)&As[s][kk][4 * bq];
            float4 w = *(const float4*)&Ws[s][kk][4 * nq];
            acc0.x = fmaf(a.x, w.x, acc0.x); acc0.y = fmaf(a.x, w.y, acc0.y);
            acc0.z = fmaf(a.x, w.z, acc0.z); acc0.w = fmaf(a.x, w.w, acc0.w);
            acc1.x = fmaf(a.y, w.x, acc1.x); acc1.y = fmaf(a.y, w.y, acc1.y);
            acc1.z = fmaf(a.y, w.z, acc1.z); acc1.w = fmaf(a.y, w.w, acc1.w);
            acc2.x = fmaf(a.z, w.x, acc2.x); acc2.y = fmaf(a.z, w.y, acc2.y);
            acc2.z = fmaf(a.z, w.z, acc2.z); acc2.w = fmaf(a.z, w.w, acc2.w);
            acc3.x = fmaf(a.w, w.x, acc3.x); acc3.y = fmaf(a.w, w.y, acc3.y);
            acc3.z = fmaf(a.w, w.z, acc3.z); acc3.w = fmaf(a.w, w.w, acc3.w);
        }
        __syncthreads();
        if (it + 1 < KT) { stage_store(s ^ 1); __syncthreads(); }
        s ^= 1;
    }

    float4 accs[4] = {acc0, acc1, acc2, acc3};
    if constexpr (MODE == 0) {
        float4 bv = *(const float4*)&bias[nt * 128 + 4 * nq];
#pragma unroll
        for (int r = 0; r < 4; ++r) {
            float4 o = accs[r];
            o.x += bv.x; o.y += bv.y; o.z += bv.z; o.w += bv.w;
            *(float4*)&Cout[(size_t)(m0 + 4 * bq + r) * ATTd + nt * 128 + 4 * nq] = o;
        }
    } else {
#pragma unroll
        for (int r = 0; r < 4; ++r) {
            int b = m0 + 4 * bq + r;
            *(float4*)&Cout[((size_t)ks * Bx + b) * 2048 + nt * 128 + 4 * nq] = accs[r];
        }
    }
}

// ---------------- fused: preds-combine(t-1) + attention step t ----------------
// grid (128, 2), block 256
__global__ __launch_bounds__(256) void attn_kernel(
    const float* __restrict__ h, const float* __restrict__ att1,
    const float* __restrict__ enc, const float* __restrict__ Wdec,
    const float* __restrict__ bdec, const float* __restrict__ wfull,
    const float* __restrict__ bfullp, const int* __restrict__ cap_len,
    const float* __restrict__ P2, const float* __restrict__ bfc,
    float* __restrict__ preds, float* __restrict__ alphas,
    float* __restrict__ ctxp, int t)
{
    int b = blockIdx.x, kh = blockIdx.y, tid = threadIdx.x;
    int declen = cap_len[b] - 1;
    // ---- preds combiner for step t-1 (bias + K-split sum + mask) ----
    if (t > 0) {
        int tp = t - 1;
        int v = kh * 1024 + 4 * tid;
        float4 o = {0.f, 0.f, 0.f, 0.f};
        if (tp < declen) {
            float4 s0 = *(const float4*)&P2[((size_t)0 * Bx + b) * 2048 + v];
            float4 s1 = *(const float4*)&P2[((size_t)1 * Bx + b) * 2048 + v];
            float4 s2 = *(const float4*)&P2[((size_t)2 * Bx + b) * 2048 + v];
            float4 s3 = *(const float4*)&P2[((size_t)3 * Bx + b) * 2048 + v];
            float4 bv = *(const float4*)&bfc[v];
            o.x = (s0.x + s1.x) + (s2.x + s3.x) + bv.x;
            o.y = (s0.y + s1.y) + (s2.y + s3.y) + bv.y;
            o.z = (s0.z + s1.z) + (s2.z + s3.z) + bv.z;
            o.w = (s0.w + s1.w) + (s2.w + s3.w) + bv.w;
        }
        *(float4*)&preds[((size_t)b * Tt + tp) * Vv + v] = o;
    }
    if (t >= declen) {
        if (kh == 0 && tid < Pp) alphas[((size_t)b * Tt + t) * Pp + tid] = 0.f;
        return;
    }
    __shared__ __align__(16) float hs[DECd];
    __shared__ __align__(16) float a2s[ATTd];
    __shared__ __align__(16) float wfs[ATTd];
    __shared__ float ev[256];
    __shared__ float red[4];
    __shared__ __align__(16) float4 ps4[4][64];
    for (int k = tid; k < DECd; k += 256) hs[k] = h[(size_t)b * DECd + k];
    wfs[tid] = wfull[tid];
    __syncthreads();
    // att2[j] = h . Wdec[j,:] + bdec[j]  (thread-per-output, 4 indep FMA chains)
    {
        const float* wrow = Wdec + (size_t)tid * DECd;
        float4 accv = {0.f, 0.f, 0.f, 0.f};
#pragma unroll 8
        for (int k4 = 0; k4 < DECd / 4; ++k4) {
            float4 w  = *(const float4*)&wrow[4 * k4];
            float4 hv = *(const float4*)&hs[4 * k4];
            accv.x = fmaf(w.x, hv.x, accv.x);
            accv.y = fmaf(w.y, hv.y, accv.y);
            accv.z = fmaf(w.z, hv.z, accv.z);
            accv.w = fmaf(w.w, hv.w, accv.w);
        }
        a2s[tid] = (accv.x + accv.y) + (accv.z + accv.w) + bdec[tid];
    }
    if (tid >= Pp) ev[tid] = -INFINITY;
    __syncthreads();
    int wave = tid >> 6, lane = tid & 63;
    float bf = bfullp[0];
    // e[p] = relu(att1 + att2) . wfull + bfull
    {
        float4 t2 = *(const float4*)&a2s[lane * 4];
        float4 wv = *(const float4*)&wfs[lane * 4];
        for (int p = wave; p < Pp; p += 4) {
            float4 av = *(const float4*)&att1[((size_t)b * Pp + p) * ATTd + lane * 4];
            float s = fmaxf(av.x + t2.x, 0.f) * wv.x + fmaxf(av.y + t2.y, 0.f) * wv.y
                    + fmaxf(av.z + t2.z, 0.f) * wv.z + fmaxf(av.w + t2.w, 0.f) * wv.w;
            s = wave_sum(s);
            if (lane == 0) ev[p] = s + bf;
        }
    }
    __syncthreads();
    // softmax over 196 (padded with -inf)
    float v = ev[tid];
    {
        float m = v;
#pragma unroll
        for (int off = 32; off > 0; off >>= 1) m = fmaxf(m, __shfl_xor(m, off, 64));
        if (lane == 0) red[wave] = m;
    }
    __syncthreads();
    float mx = fmaxf(fmaxf(red[0], red[1]), fmaxf(red[2], red[3]));
    float ex = __expf(v - mx);
    __syncthreads();
    {
        float sm = ex;
#pragma unroll
        for (int off = 32; off > 0; off >>= 1) sm += __shfl_xor(sm, off, 64);
        if (lane == 0) red[wave] = sm;
    }
    __syncthreads();
    float inv = 1.f / (red[0] + red[1] + red[2] + red[3]);
    float alpha = ex * inv;
    ev[tid] = alpha;
    if (kh == 0 && tid < Pp) alphas[((size_t)b * Tt + t) * Pp + tid] = alpha;
    __syncthreads();
    // ctx: wave q covers p in [q*49, q*49+49); thread covers 4 k's (float4)
    {
        int q = tid >> 6, kq = tid & 63;
        const float* eb = enc + (size_t)b * Pp * ENCd + kh * 256 + 4 * kq;
        float4 a4 = {0.f, 0.f, 0.f, 0.f};
        int p0 = q * 49;
#pragma unroll 7
        for (int i = 0; i < 49; ++i) {
            float al = ev[p0 + i];
            float4 e4 = *(const float4*)&eb[(size_t)(p0 + i) * ENCd];
            a4.x = fmaf(al, e4.x, a4.x);
            a4.y = fmaf(al, e4.y, a4.y);
            a4.z = fmaf(al, e4.z, a4.z);
            a4.w = fmaf(al, e4.w, a4.w);
        }
        ps4[q][kq] = a4;
    }
    __syncthreads();
    {
        const float* pf = (const float*)ps4;
        float ssum = (pf[tid] + pf[256 + tid]) + (pf[512 + tid] + pf[768 + tid]);
        ctxp[(size_t)b * ENCd + kh * 256 + tid] = ssum;
    }
}

// ---------------- LSTM combiner: sum gate partials, nonlinearity, in-place h/c ----------------
// grid 256 = (b, j-half), block 256
__global__ __launch_bounds__(256) void lstm_comb_kernel(
    const float* __restrict__ P, const float* __restrict__ bih,
    const float* __restrict__ bhh, const int* __restrict__ cap_len,
    float* __restrict__ h, float* __restrict__ c, int t)
{
    int b = blockIdx.x >> 1, jh = blockIdx.x & 1;
    if (t >= cap_len[b] - 1) return;
    int j = jh * 256 + threadIdx.x;
    int colp = (j >> 5) * 128 + 4 * (j & 31);
    float4 s = {0.f, 0.f, 0.f, 0.f};
#pragma unroll
    for (int ksi = 0; ksi < 4; ++ksi) {
        float4 pv = *(const float4*)&P[((size_t)ksi * Bx + b) * 2048 + colp];
        s.x += pv.x; s.y += pv.y; s.z += pv.z; s.w += pv.w;
    }
    float gi = s.x + bih[j]            + bhh[j];
    float gf = s.y + bih[DECd + j]     + bhh[DECd + j];
    float gg = s.z + bih[2 * DECd + j] + bhh[2 * DECd + j];
    float go = s.w + bih[3 * DECd + j] + bhh[3 * DECd + j];
    float cold = c[(size_t)b * DECd + j];
    float cn = fsigmoid(gf) * cold + fsigmoid(gi) * ftanh(gg);
    float hn = fsigmoid(go) * ftanh(cn);
    h[(size_t)b * DECd + j] = hn;
    c[(size_t)b * DECd + j] = cn;
}

// ---------------- standalone preds combiner (final step) ----------------
__global__ __launch_bounds__(256) void preds_comb_kernel(
    const float* __restrict__ P2, const float* __restrict__ bfc,
    const int* __restrict__ cap_len, float* __restrict__ preds, int t)
{
    int b = blockIdx.x, kh = blockIdx.y, tid = threadIdx.x;
    int v = kh * 1024 + 4 * tid;
    float4 o = {0.f, 0.f, 0.f, 0.f};
    if (t < cap_len[b] - 1) {
        float4 s0 = *(const float4*)&P2[((size_t)0 * Bx + b) * 2048 + v];
        float4 s1 = *(const float4*)&P2[((size_t)1 * Bx + b) * 2048 + v];
        float4 s2 = *(const float4*)&P2[((size_t)2 * Bx + b) * 2048 + v];
        float4 s3 = *(const float4*)&P2[((size_t)3 * Bx + b) * 2048 + v];
        float4 bv = *(const float4*)&bfc[v];
        o.x = (s0.x + s1.x) + (s2.x + s3.x) + bv.x;
        o.y = (s0.y + s1.y) + (s2.y + s3.y) + bv.y;
        o.z = (s0.z + s1.z) + (s2.z + s3.z) + bv.z;
        o.w = (s0.w + s1.w) + (s2.w + s3.w) + bv.w;
    }
    *(float4*)&preds[((size_t)b * Tt + t) * Vv + v] = o;
}

extern "C" void kernel_launch(void* const* d_in, const int* in_sizes, int n_in,
                              void* d_out, int out_size, void* d_ws, size_t ws_size,
                              hipStream_t stream) {
    const float* enc      = (const float*)d_in[0];
    const int*   caps     = (const int*)d_in[1];
    const int*   cap_len  = (const int*)d_in[2];
    const float* embedding= (const float*)d_in[3];
    const float* Wenc     = (const float*)d_in[4];
    const float* benc     = (const float*)d_in[5];
    const float* Wdec     = (const float*)d_in[6];
    const float* bdec     = (const float*)d_in[7];
    const float* wfull    = (const float*)d_in[8];
    const float* bfull    = (const float*)d_in[9];
    const float* Wih      = (const float*)d_in[10];
    const float* bih      = (const float*)d_in[11];
    const float* Whh      = (const float*)d_in[12];
    const float* bhh      = (const float*)d_in[13];
    const float* Winh     = (const float*)d_in[14];
    const float* binh     = (const float*)d_in[15];
    const float* Winc     = (const float*)d_in[16];
    const float* binc     = (const float*)d_in[17];
    const float* Wfc      = (const float*)d_in[18];
    const float* bfc      = (const float*)d_in[19];

    float* preds  = (float*)d_out;                         // B*T*V
    float* alphas = preds + (size_t)Bx * Tt * Vv;          // B*T*P

    float* ws   = (float*)d_ws;
    float* att1 = ws;                                      // 25088*256
    float* P    = att1 + (size_t)Bx * Pp * ATTd;           // 4*128*2048
    float* P2   = P + (size_t)4 * Bx * 2048;               // 4*128*2048
    float* hbuf = P2 + (size_t)4 * Bx * 2048;
    float* cbuf = hbuf + (size_t)Bx * DECd;
    float* ctx  = cbuf + (size_t)Bx * DECd;

    init_state_kernel<<<Bx, 256, 0, stream>>>(enc, Winh, binh, Winc, binc, hbuf, cbuf);
    gemm_kernel<0><<<dim3(2, 784), 256, 0, stream>>>(enc, Wenc, nullptr, benc,
                                                     nullptr, nullptr, nullptr, nullptr,
                                                     att1, 0);

    for (int t = 0; t < Tt; ++t) {
        attn_kernel<<<dim3(Bx, 2), 256, 0, stream>>>(hbuf, att1, enc, Wdec, bdec, wfull,
                                                     bfull, cap_len, P2, bfc,
                                                     preds, alphas, ctx, t);
        gemm_kernel<1><<<dim3(64, 4), 256, 0, stream>>>(hbuf, Wih, Whh, nullptr,
                                                        ctx, embedding, caps, cap_len,
                                                        P, t);
        lstm_comb_kernel<<<256, 256, 0, stream>>>(P, bih, bhh, cap_len, hbuf, cbuf, t);
        gemm_kernel<2><<<dim3(64, 4), 256, 0, stream>>>(hbuf, Wfc, nullptr, nullptr,
                                                        nullptr, nullptr, nullptr, cap_len,
                                                        P2, t);
    }
    preds_comb_kernel<<<dim3(Bx, 2), 256, 0, stream>>>(P2, bfc, cap_len, preds, Tt - 1);
}